// Round 1
// baseline (72.246 us; speedup 1.0000x reference)
//
#include <hip/hip_runtime.h>

// Gemma4VisionPooler: B=16, S=4096 (64x64 grid), H=1152, OUT=256, k=4.
// Output[b,o,:] = (sum of the 16 rows x[b,s,:] whose bucket kidx(s)==o) / 16 * sqrt(H)
// Bucket: kidx = (px/k) + (max_x/k)*(py/k), px,py from position_ids (clamped >=0),
// padding rows (pos == [-1,-1]) contribute nothing (reference zeroes them).

#define BB 16
#define SS 4096
#define HH 1152
#define OUTL 256
#define KK 4
#define K2 16
#define H4 (HH / 4)   // 288 float4 per row

// ---------------- Kernel A: per-batch max_x = max(clamp(pos_x,0)) + 1 ----------------
__global__ __launch_bounds__(256) void maxx_kernel(const int* __restrict__ pos,
                                                   int* __restrict__ maxx) {
    int b = blockIdx.x;
    int t = threadIdx.x;
    int m = 0;
    for (int s = t; s < SS; s += 256) {
        int px = pos[((size_t)b * SS + s) * 2];
        if (px > m) m = px;  // padding px=-1 clamps below 0 anyway
    }
    __shared__ int red[256];
    red[t] = m;
    __syncthreads();
    for (int w = 128; w > 0; w >>= 1) {
        if (t < w) red[t] = max(red[t], red[t + w]);
        __syncthreads();
    }
    if (t == 0) maxx[b] = red[0] + 1;
}

// ---------------- Kernel B: build inverse map bucket -> source rows ----------------
__global__ __launch_bounds__(256) void build_kernel(const int* __restrict__ pos,
                                                    const int* __restrict__ maxx,
                                                    int* __restrict__ counts,
                                                    int* __restrict__ rows) {
    int idx = blockIdx.x * 256 + threadIdx.x;
    if (idx >= BB * SS) return;
    int b = idx / SS, s = idx % SS;
    int px = pos[(size_t)idx * 2];
    int py = pos[(size_t)idx * 2 + 1];
    if (px == -1 && py == -1) return;  // padding row: contributes zero
    px = max(px, 0);
    py = max(py, 0);
    int mx = maxx[b];
    int kidx = px / KK + (mx / KK) * (py / KK);
    if (kidx < 0 || kidx >= OUTL) return;  // safety clamp
    int slot = atomicAdd(&counts[b * OUTL + kidx], 1);
    if (slot < K2) rows[((size_t)b * OUTL + kidx) * K2 + slot] = s;
}

// ---------------- Kernel C: heavy gather (memory-bound) ----------------
__global__ __launch_bounds__(256) void gather_kernel(const float* __restrict__ x,
                                                     const int* __restrict__ counts,
                                                     const int* __restrict__ rows,
                                                     float* __restrict__ out) {
    int idx = blockIdx.x * 256 + threadIdx.x;  // [0, B*OUT*H4)
    int c = idx % H4;
    int bo = idx / H4;           // b*OUT + o
    int b = bo / OUTL;
    const float4* x4 = reinterpret_cast<const float4*>(x) + (size_t)b * SS * H4;
    int cnt = counts[bo];
    if (cnt > K2) cnt = K2;
    const int* rl = rows + (size_t)bo * K2;
    float4 acc = {0.f, 0.f, 0.f, 0.f};
    if (cnt == K2) {
#pragma unroll
        for (int j = 0; j < K2; ++j) {
            int row = rl[j];
            float4 v = x4[(size_t)row * H4 + c];
            acc.x += v.x; acc.y += v.y; acc.z += v.z; acc.w += v.w;
        }
    } else {
        for (int j = 0; j < cnt; ++j) {
            int row = rl[j];
            float4 v = x4[(size_t)row * H4 + c];
            acc.x += v.x; acc.y += v.y; acc.z += v.z; acc.w += v.w;
        }
    }
    // scale = sqrt(H) / k^2 = sqrt(1152)/16
    const float scale = 33.94112549695428f / 16.0f;
    float4 r;
    r.x = acc.x * scale; r.y = acc.y * scale; r.z = acc.z * scale; r.w = acc.w * scale;
    reinterpret_cast<float4*>(out)[idx] = r;
}

extern "C" void kernel_launch(void* const* d_in, const int* in_sizes, int n_in,
                              void* d_out, int out_size, void* d_ws, size_t ws_size,
                              hipStream_t stream) {
    const float* x = (const float*)d_in[0];
    const int* pos = (const int*)d_in[1];
    // d_in[2] = output_length (device scalar) — fixed at 256 for this problem shape.
    float* out = (float*)d_out;

    // Workspace layout (ints):
    //   counts: B*OUT            = 4096
    //   rows:   B*OUT*K2         = 65536
    //   maxx:   B                = 16
    int* counts = (int*)d_ws;
    int* rows = counts + BB * OUTL;
    int* maxx = rows + (size_t)BB * OUTL * K2;

    hipMemsetAsync(counts, 0, (size_t)BB * OUTL * sizeof(int), stream);

    maxx_kernel<<<BB, 256, 0, stream>>>(pos, maxx);

    int nbs = (BB * SS + 255) / 256;  // 256 blocks
    build_kernel<<<nbs, 256, 0, stream>>>(pos, maxx, counts, rows);

    int total4 = BB * OUTL * H4;      // 1,179,648 float4 outputs
    int nbg = total4 / 256;           // 4608 blocks (divides exactly)
    gather_kernel<<<nbg, 256, 0, stream>>>(x, counts, rows, out);
}

// Round 2
// 64.982 us; speedup vs baseline: 1.1118x; 1.1118x over previous
//
#include <hip/hip_runtime.h>

// Gemma4VisionPooler: B=16, S=4096 (64x64 grid), H=1152, OUT=256, k=4.
// out[b,o,:] = (sum over the <=16 rows x[b,s,:] with bucket(s)==o) * sqrt(H)/16
// bucket = (px/k) + (max_x/k)*(py/k); pos clamped >=0; padding rows ([-1,-1]) skipped.

#define BB 16
#define SS 4096
#define HH 1152
#define OUTL 256
#define KK 4
#define K2 16
#define H4 (HH / 4)     // 288 float4 per row
#define HP (H4 / 2)     // 144 float4-pairs per row

// ---- Fused prologue: per-batch max_x + bucket->rows inverse map (LDS) ----
__global__ __launch_bounds__(256) void build_fused(const int* __restrict__ pos,
                                                   int* __restrict__ counts,
                                                   int* __restrict__ rows) {
    int b = blockIdx.x;
    int t = threadIdx.x;
    const int2* p2 = reinterpret_cast<const int2*>(pos) + (size_t)b * SS;

    // phase 1: max px (padding px=-1 never wins vs init 0)
    int m = 0;
    for (int s = t; s < SS; s += 256) {
        int px = p2[s].x;
        if (px > m) m = px;
    }
    __shared__ int red[256];
    red[t] = m;
    __syncthreads();
    for (int w = 128; w > 0; w >>= 1) {
        if (t < w) red[t] = max(red[t], red[t + w]);
        __syncthreads();
    }
    __shared__ int smx;
    if (t == 0) smx = red[0] + 1;

    // phase 2: LDS counts + row lists
    __shared__ int lcnt[OUTL];
    __shared__ int lrows[OUTL * K2];
    lcnt[t] = 0;
    __syncthreads();
    int mxk = smx / KK;
    for (int s = t; s < SS; s += 256) {
        int2 xy = p2[s];
        if (xy.x == -1 && xy.y == -1) continue;  // padding row
        int px = max(xy.x, 0), py = max(xy.y, 0);
        int kidx = px / KK + mxk * (py / KK);
        if ((unsigned)kidx < OUTL) {
            int slot = atomicAdd(&lcnt[kidx], 1);
            if (slot < K2) lrows[kidx * K2 + slot] = s;
        }
    }
    __syncthreads();

    // phase 3: coalesced writeout
    counts[b * OUTL + t] = lcnt[t];
    int* rb = rows + (size_t)b * OUTL * K2;
    for (int i = t; i < OUTL * K2; i += 256) rb[i] = lrows[i];
}

// ---- Heavy gather: 2 adjacent float4 (32 B) per thread ----
__global__ __launch_bounds__(256) void gather_kernel(const float* __restrict__ x,
                                                     const int* __restrict__ counts,
                                                     const int* __restrict__ rows,
                                                     float* __restrict__ out) {
    int idx = blockIdx.x * 256 + threadIdx.x;  // [0, B*OUT*HP)
    int c2 = idx % HP;
    int bo = idx / HP;            // b*OUT + o
    int b = bo / OUTL;
    int col = c2 * 2;             // float4 column pair (col, col+1)

    const float4* x4 = reinterpret_cast<const float4*>(x) + (size_t)b * SS * H4 + col;
    const int* rl = rows + (size_t)bo * K2;
    int cnt = counts[bo];
    if (cnt > K2) cnt = K2;

    float4 a0 = {0.f, 0.f, 0.f, 0.f};
    float4 a1 = {0.f, 0.f, 0.f, 0.f};
    if (cnt == K2) {
#pragma unroll
        for (int j = 0; j < K2; ++j) {
            const float4* p = x4 + (size_t)rl[j] * H4;
            float4 v0 = p[0], v1 = p[1];
            a0.x += v0.x; a0.y += v0.y; a0.z += v0.z; a0.w += v0.w;
            a1.x += v1.x; a1.y += v1.y; a1.z += v1.z; a1.w += v1.w;
        }
    } else {
        for (int j = 0; j < cnt; ++j) {
            const float4* p = x4 + (size_t)rl[j] * H4;
            float4 v0 = p[0], v1 = p[1];
            a0.x += v0.x; a0.y += v0.y; a0.z += v0.z; a0.w += v0.w;
            a1.x += v1.x; a1.y += v1.y; a1.z += v1.z; a1.w += v1.w;
        }
    }
    const float scale = 2.1213203435596424f;  // sqrt(1152)/16
    float4 r0, r1;
    r0.x = a0.x * scale; r0.y = a0.y * scale; r0.z = a0.z * scale; r0.w = a0.w * scale;
    r1.x = a1.x * scale; r1.y = a1.y * scale; r1.z = a1.z * scale; r1.w = a1.w * scale;
    float4* o4 = reinterpret_cast<float4*>(out) + (size_t)bo * H4 + col;
    o4[0] = r0;
    o4[1] = r1;
}

extern "C" void kernel_launch(void* const* d_in, const int* in_sizes, int n_in,
                              void* d_out, int out_size, void* d_ws, size_t ws_size,
                              hipStream_t stream) {
    const float* x = (const float*)d_in[0];
    const int* pos = (const int*)d_in[1];
    float* out = (float*)d_out;

    // ws: counts [B*OUT] ints, rows [B*OUT*K2] ints
    int* counts = (int*)d_ws;
    int* rows = counts + BB * OUTL;

    build_fused<<<BB, 256, 0, stream>>>(pos, counts, rows);

    int total = BB * OUTL * HP;     // 589,824 threads
    gather_kernel<<<total / 256, 256, 0, stream>>>(x, counts, rows, out);
}